// Round 13
// baseline (574.257 us; speedup 1.0000x reference)
//
#include <hip/hip_runtime.h>
#include <hip/hip_bf16.h>

#define NTOK 8192
#define DIM 1024
#define NEXP 8
#define NT 256   // virtual K tiles: 16 segments (expert x half) x 16 tiles of BK=64
#define BK 64

typedef float f32x4 __attribute__((ext_vector_type(4)));
typedef short s16x8 __attribute__((ext_vector_type(8)));
typedef unsigned short u16;
typedef unsigned short u16x4 __attribute__((ext_vector_type(4)));

__device__ __forceinline__ u16 f2bf(float f) {
    __hip_bfloat16 h = __float2bfloat16(f);
    return *reinterpret_cast<u16*>(&h);
}
__device__ __forceinline__ float bf2f(u16 u) {
    unsigned v = ((unsigned)u) << 16;
    return __uint_as_float(v);
}

#define GLOAD16(gsrc, ldst)                                                     \
    __builtin_amdgcn_global_load_lds(                                           \
        (const __attribute__((address_space(1))) void*)(gsrc),                  \
        (__attribute__((address_space(3))) void*)(ldst), 16, 0, 0)

#define MFMA16(a, b, c) __builtin_amdgcn_mfma_f32_16x16x32_bf16((a), (b), (c), 0, 0, 0)
#define SGB() __builtin_amdgcn_sched_barrier(0)

// ---------------- gates: softmax(z_flat @ Wg^T + bg) ----------------
__global__ __launch_bounds__(256) void gates_kernel(
    const float* __restrict__ zr, const float* __restrict__ zi,
    const float* __restrict__ Wg, const float* __restrict__ bg,
    float* __restrict__ gates)
{
    const int wave = threadIdx.x >> 6, lane = threadIdx.x & 63;
    const int n = blockIdx.x * 4 + wave;

    float v[32];
    const float* zrp = zr + (size_t)n * DIM;
    const float* zip = zi + (size_t)n * DIM;
#pragma unroll
    for (int j = 0; j < 16; ++j) v[j] = zrp[j * 64 + lane];
#pragma unroll
    for (int j = 0; j < 16; ++j) v[16 + j] = zip[j * 64 + lane];

    float s[NEXP];
#pragma unroll
    for (int e = 0; e < NEXP; ++e) {
        const float* wrow = Wg + (size_t)e * (2 * DIM);
        float a = 0.f;
#pragma unroll
        for (int j = 0; j < 32; ++j) a += v[j] * wrow[j * 64 + lane];
#pragma unroll
        for (int m = 32; m; m >>= 1) a += __shfl_xor(a, m);
        s[e] = a + bg[e];
    }
    float mx = s[0];
#pragma unroll
    for (int e = 1; e < NEXP; ++e) mx = fmaxf(mx, s[e]);
    float p[NEXP], sum = 0.f;
#pragma unroll
    for (int e = 0; e < NEXP; ++e) { p[e] = expf(s[e] - mx); sum += p[e]; }
    const float inv = 1.f / sum;
    if (lane == 0) {
#pragma unroll
        for (int e = 0; e < NEXP; ++e) gates[(size_t)n * NEXP + e] = p[e] * inv;
    }
}

// ---------------- fp32 -> bf16 conversion (z and W) ----------------
__global__ __launch_bounds__(256) void cvt4_kernel(
    const float* __restrict__ zr, const float* __restrict__ zi,
    const float* __restrict__ Wr, const float* __restrict__ Wi,
    u16* __restrict__ zr16, u16* __restrict__ zi16,
    u16* __restrict__ Wr16, u16* __restrict__ Wi16)
{
    const size_t total = (size_t)NEXP * DIM * DIM / 4;
    for (size_t i = (size_t)blockIdx.x * 256 + threadIdx.x; i < total;
         i += (size_t)gridDim.x * 256) {
        f32x4 a = ((const f32x4*)zr)[i];
        f32x4 b = ((const f32x4*)zi)[i];
        f32x4 c = ((const f32x4*)Wr)[i];
        f32x4 d = ((const f32x4*)Wi)[i];
        u16x4 pa, pb, pc, pd;
#pragma unroll
        for (int j = 0; j < 4; ++j) {
            pa[j] = f2bf(a[j]); pb[j] = f2bf(b[j]);
            pc[j] = f2bf(c[j]); pd[j] = f2bf(d[j]);
        }
        ((u16x4*)zr16)[i] = pa;
        ((u16x4*)zi16)[i] = pb;
        ((u16x4*)Wr16)[i] = pc;
        ((u16x4*)Wi16)[i] = pd;
    }
}

// ---------------- main MoE GEMM: 256x256, m201-phase mechanics ---------------
// 512 threads = 8 waves (2M x 4N), per-wave 128x64. Virtual K = 16 seg x 1024.
// LDS 128 KB: A dbuf 2x32KB (VALU cvt, gate*sign folded), B dbuf 2x32KB
// (gload_lds, t+1). Per tile, TWO phase-pairs, each with the m201 discipline:
//   {issue 12 ds_reads} -> lgkmcnt(8) throttle -> RAW barrier -> lgkmcnt(0)
//   -> pure 32-MFMA setprio window -> RAW barrier.
// Waves cross the barrier with reads in flight (barrier = arrival, not
// completion); each wave waits only its OWN reads -> wave-skew overlaps the
// LDS queue with the MFMA pipe (phase ~ max(LDS,MFMA), not sum).
// cvt+writes issue in ph23 AFTER its reads (ga vmcnt covered by ph01);
// vmcnt(0) only at tile tail (B gloads issued at tile top, ~2800 cy cover).
__global__ __launch_bounds__(512, 2) void moe_gemm13(
    const u16* __restrict__ zr16, const u16* __restrict__ zi16,
    const u16* __restrict__ Wr16, const u16* __restrict__ Wi16,
    const float* __restrict__ gates, float* __restrict__ out)
{
    extern __shared__ u16 lds[];  // A: slot*16384 (s=0,1); B: 32768 + slot*16384

    // bm-local XCD remap: hw xcd = linear%8 owns bm in [xcd*4, xcd*4+4).
    const int linear = blockIdx.x + 32 * (blockIdx.y + 4 * blockIdx.z);
    const int xcd = linear & 7;
    const int bm = xcd * 4 + ((linear >> 3) & 3);
    const int grp2 = linear >> 5;   // 0..7
    const int bn = grp2 & 3;
    const int sel = grp2 >> 2;

    const int tid = threadIdx.x;
    const int lane = tid & 63;
    const int wid = tid >> 6;
    const int wr = wid >> 2;   // 0..1
    const int wc = wid & 3;    // 0..3

    // ---- staging addressing (swizzle chunk c ^= row&7, inverse on source) ----
    const int srow = tid >> 3;
    const int schunk = (tid & 7) ^ (srow & 7);
    int arow[4], gidx[4], brow[4];
#pragma unroll
    for (int j = 0; j < 4; ++j) {
        const int gr = bm * 256 + srow + j * 64;
        arow[j] = gr * DIM + schunk * 8;
        gidx[j] = gr * NEXP;
        brow[j] = (bn * 256 + srow + j * 64) * DIM + schunk * 8;
    }

    // ---- fragment read addressing (elems) ----
    const int cg = lane >> 4;
    const int l7 = lane & 7;
    const int ach0 = (cg ^ l7) * 8;
    const int ach1 = ((4 + cg) ^ l7) * 8;
    const int arbase = (wr * 128 + (lane & 15)) * BK;
    const int brbase = (wc * 64 + (lane & 15)) * BK;

    f32x4 acc[8][4];
#pragma unroll
    for (int m = 0; m < 8; ++m)
#pragma unroll
        for (int n = 0; n < 4; ++n) acc[m][n] = (f32x4){0.f, 0.f, 0.f, 0.f};

    // ---- segment state (tracks tile t+1) ----
    const u16* Asrc = sel ? zi16 : zr16;   // seg 0
    const u16* Bseg = Wr16;                // seg 0
    float sg[4];
#pragma unroll
    for (int j = 0; j < 4; ++j) sg[j] = gates[gidx[j]];

    // ---- prologue: A(0)->slot0 (cvt); B(0)->bslot0 (gloads) ----
    {
        s16x8 ga0[4];
#pragma unroll
        for (int j = 0; j < 4; ++j) ga0[j] = *(const s16x8*)(Asrc + arow[j]);
#pragma unroll
        for (int q = 0; q < 4; ++q)
            GLOAD16(Bseg + brow[q], &lds[32768 + (q * 512 + tid) * 8]);
#pragma unroll
        for (int j = 0; j < 4; ++j) {
            s16x8 w;
#pragma unroll
            for (int e = 0; e < 8; ++e)
                w[e] = (short)f2bf(bf2f((u16)ga0[j][e]) * sg[j]);
            *(s16x8*)&lds[(tid + j * 512) * 8] = w;
        }
        asm volatile("s_waitcnt vmcnt(0) lgkmcnt(0)" ::: "memory");
        __builtin_amdgcn_s_barrier();
    }

    int buf = 0;
#pragma unroll 1
    for (int t = 0; t < NT; ++t) {
        const int t1 = t + 1;
        if ((t1 & 15) == 0) {  // segment state for tile t+1
            const int seg = t1 >> 4;
            const int e = (seg >> 1) & 7;   // seg 16 (dead tile) wraps, unused
            const int half = seg & 1;
            Asrc = (half ^ sel) ? zi16 : zr16;
            Bseg = (half ? Wi16 : Wr16) + (size_t)e * DIM * DIM;
            const float sgn = (sel == 0 && half == 1) ? -1.f : 1.f;
#pragma unroll
            for (int j = 0; j < 4; ++j) sg[j] = sgn * gates[gidx[j] + e];
        }
        const int ka = (t1 & 15) << 6;               // staging k base (elems)
        const int ab = buf * 16384 + arbase;         // A read base
        const int bb = 32768 + buf * 16384 + brbase; // B read base
        const int sa = (buf ^ 1) * 16384;            // A staging dest
        const int sb = 32768 + (buf ^ 1) * 16384;    // B staging dest

        // ---- tile top: ga(t+1) reg loads FIRST, then B(t+1) gloads ----
        s16x8 ga[4];
#pragma unroll
        for (int j = 0; j < 4; ++j) ga[j] = *(const s16x8*)(Asrc + arow[j] + ka);
        GLOAD16(Bseg + brow[0] + ka, &lds[sb + (0 * 512 + tid) * 8]);
        GLOAD16(Bseg + brow[1] + ka, &lds[sb + (1 * 512 + tid) * 8]);
        GLOAD16(Bseg + brow[2] + ka, &lds[sb + (2 * 512 + tid) * 8]);
        GLOAD16(Bseg + brow[3] + ka, &lds[sb + (3 * 512 + tid) * 8]);

        // ================= PH01: ks0 =================
        s16x8 b0[4], a01[8];
#pragma unroll
        for (int n = 0; n < 4; ++n) b0[n] = *(const s16x8*)&lds[bb + n * 1024 + ach0];
#pragma unroll
        for (int m = 0; m < 8; ++m) a01[m] = *(const s16x8*)&lds[ab + m * 1024 + ach0];
        asm volatile("s_waitcnt lgkmcnt(8)" ::: "memory");  // skew throttle
        SGB();
        __builtin_amdgcn_s_barrier();          // arrival-only; reads in flight
        asm volatile("s_waitcnt lgkmcnt(0)" ::: "memory");  // own reads only
        SGB();
        __builtin_amdgcn_s_setprio(1);
#pragma unroll
        for (int m = 0; m < 8; ++m)
#pragma unroll
            for (int n = 0; n < 4; ++n) acc[m][n] = MFMA16(a01[m], b0[n], acc[m][n]);
        __builtin_amdgcn_s_setprio(0);
        SGB();
        __builtin_amdgcn_s_barrier();

        // ================= PH23: ks1 + A-staging =================
        s16x8 b1[4], a23[8];
#pragma unroll
        for (int n = 0; n < 4; ++n) b1[n] = *(const s16x8*)&lds[bb + n * 1024 + ach1];
#pragma unroll
        for (int m = 0; m < 8; ++m) a23[m] = *(const s16x8*)&lds[ab + m * 1024 + ach1];
        // cvt + writes AFTER the reads (ga's vmcnt wait covered by PH01)
#pragma unroll
        for (int j = 0; j < 4; ++j) {
            s16x8 w;
#pragma unroll
            for (int e = 0; e < 8; ++e)
                w[e] = (short)f2bf(bf2f((u16)ga[j][e]) * sg[j]);
            *(s16x8*)&lds[sa + (tid + j * 512) * 8] = w;
        }
        asm volatile("s_waitcnt lgkmcnt(8)" ::: "memory");
        SGB();
        __builtin_amdgcn_s_barrier();
        asm volatile("s_waitcnt lgkmcnt(0)" ::: "memory");
        SGB();
        __builtin_amdgcn_s_setprio(1);
#pragma unroll
        for (int m = 0; m < 8; ++m)
#pragma unroll
            for (int n = 0; n < 4; ++n) acc[m][n] = MFMA16(a23[m], b1[n], acc[m][n]);
        __builtin_amdgcn_s_setprio(0);
        // B(t+1) gloads drained (issued at tile top, whole-tile cover — free)
        asm volatile("s_waitcnt vmcnt(0)" ::: "memory");
        SGB();
        __builtin_amdgcn_s_barrier();

        buf ^= 1;
    }

    // ---- epilogue: C[row][col], col=lane&15, row=(lane>>4)*4+j (m89 layout) ----
    float* op = out + (size_t)sel * NTOK * DIM;
    const int col0 = bn * 256 + wc * 64 + (lane & 15);
    const int row0 = bm * 256 + wr * 128 + ((lane >> 4) << 2);
#pragma unroll
    for (int m = 0; m < 8; ++m)
#pragma unroll
        for (int n = 0; n < 4; ++n)
#pragma unroll
            for (int j = 0; j < 4; ++j)
                op[(size_t)(row0 + m * 16 + j) * DIM + col0 + n * 16] = acc[m][n][j];
}

extern "C" void kernel_launch(void* const* d_in, const int* in_sizes, int n_in,
                              void* d_out, int out_size, void* d_ws, size_t ws_size,
                              hipStream_t stream) {
    const float* zr = (const float*)d_in[0];
    const float* zi = (const float*)d_in[1];
    const float* Wg = (const float*)d_in[2];
    const float* bg = (const float*)d_in[3];
    const float* Wr = (const float*)d_in[4];
    const float* Wi = (const float*)d_in[5];
    float* out = (float*)d_out;

    const size_t NELEM = (size_t)NEXP * DIM * DIM;  // == NTOK*DIM
    u16* zr16 = (u16*)d_ws;
    u16* zi16 = zr16 + NELEM;
    u16* Wr16 = zi16 + NELEM;
    u16* Wi16 = Wr16 + NELEM;
    float* gates = (float*)(Wi16 + NELEM);

    cvt4_kernel<<<2048, 256, 0, stream>>>(zr, zi, Wr, Wi, zr16, zi16, Wr16, Wi16);
    gates_kernel<<<NTOK / 4, 256, 0, stream>>>(zr, zi, Wg, bg, gates);

    hipFuncSetAttribute((const void*)moe_gemm13,
                        hipFuncAttributeMaxDynamicSharedMemorySize, 131072);
    dim3 grid(NTOK / 256, DIM / 256, 2);
    moe_gemm13<<<grid, 512, 131072, stream>>>(zr16, zi16, Wr16, Wi16, gates, out);
}

// Round 14
// 537.587 us; speedup vs baseline: 1.0682x; 1.0682x over previous
//
#include <hip/hip_runtime.h>
#include <hip/hip_bf16.h>

#define NTOK 8192
#define DIM 1024
#define NEXP 8
#define NT 256   // virtual K tiles: 16 segments (expert x half) x 16 tiles of BK=64
#define BK 64
#define NELEMZ ((size_t)NTOK * DIM)   // == NEXP*DIM*DIM

typedef float f32x4 __attribute__((ext_vector_type(4)));
typedef short s16x8 __attribute__((ext_vector_type(8)));
typedef unsigned short u16;
typedef unsigned short u16x4 __attribute__((ext_vector_type(4)));

__device__ __forceinline__ u16 f2bf(float f) {
    __hip_bfloat16 h = __float2bfloat16(f);
    return *reinterpret_cast<u16*>(&h);
}
__device__ __forceinline__ float bf2f(u16 u) {
    unsigned v = ((unsigned)u) << 16;
    return __uint_as_float(v);
}

#define GLOAD16(gsrc, ldst)                                                     \
    __builtin_amdgcn_global_load_lds(                                           \
        (const __attribute__((address_space(1))) void*)(gsrc),                  \
        (__attribute__((address_space(3))) void*)(ldst), 16, 0, 0)

#define MFMA16(a, b, c) __builtin_amdgcn_mfma_f32_16x16x32_bf16((a), (b), (c), 0, 0, 0)
#define SGB() __builtin_amdgcn_sched_barrier(0)

// ---------------- gates: softmax(z_flat @ Wg^T + bg) ----------------
__global__ __launch_bounds__(256) void gates_kernel(
    const float* __restrict__ zr, const float* __restrict__ zi,
    const float* __restrict__ Wg, const float* __restrict__ bg,
    float* __restrict__ gates)
{
    const int wave = threadIdx.x >> 6, lane = threadIdx.x & 63;
    const int n = blockIdx.x * 4 + wave;

    float v[32];
    const float* zrp = zr + (size_t)n * DIM;
    const float* zip = zi + (size_t)n * DIM;
#pragma unroll
    for (int j = 0; j < 16; ++j) v[j] = zrp[j * 64 + lane];
#pragma unroll
    for (int j = 0; j < 16; ++j) v[16 + j] = zip[j * 64 + lane];

    float s[NEXP];
#pragma unroll
    for (int e = 0; e < NEXP; ++e) {
        const float* wrow = Wg + (size_t)e * (2 * DIM);
        float a = 0.f;
#pragma unroll
        for (int j = 0; j < 32; ++j) a += v[j] * wrow[j * 64 + lane];
#pragma unroll
        for (int m = 32; m; m >>= 1) a += __shfl_xor(a, m);
        s[e] = a + bg[e];
    }
    float mx = s[0];
#pragma unroll
    for (int e = 1; e < NEXP; ++e) mx = fmaxf(mx, s[e]);
    float p[NEXP], sum = 0.f;
#pragma unroll
    for (int e = 0; e < NEXP; ++e) { p[e] = expf(s[e] - mx); sum += p[e]; }
    const float inv = 1.f / sum;
    if (lane == 0) {
#pragma unroll
        for (int e = 0; e < NEXP; ++e) gates[(size_t)n * NEXP + e] = p[e] * inv;
    }
}

// ---------------- prescale: zvar[e] = bf16(g[n,e]*zr), zvar[8+e] = g*zi ------
__global__ __launch_bounds__(256) void prez_kernel(
    const float* __restrict__ zr, const float* __restrict__ zi,
    const float* __restrict__ gates, u16* __restrict__ zvar)
{
    const size_t total = NELEMZ / 4;
    for (size_t i = (size_t)blockIdx.x * 256 + threadIdx.x; i < total;
         i += (size_t)gridDim.x * 256) {
        const int n = (int)(i >> 8);            // DIM/4 = 256 chunks per row
        f32x4 a = ((const f32x4*)zr)[i];
        f32x4 b = ((const f32x4*)zi)[i];
        float g[NEXP];
#pragma unroll
        for (int e = 0; e < NEXP; ++e) g[e] = gates[(size_t)n * NEXP + e];
#pragma unroll
        for (int e = 0; e < NEXP; ++e) {
            u16x4 pa, pb;
#pragma unroll
            for (int j = 0; j < 4; ++j) {
                pa[j] = f2bf(a[j] * g[e]);
                pb[j] = f2bf(b[j] * g[e]);
            }
            ((u16x4*)(zvar + (size_t)e * NELEMZ))[i] = pa;
            ((u16x4*)(zvar + (size_t)(8 + e) * NELEMZ))[i] = pb;
        }
    }
}

// ---------------- W cvt: Wr16, Wi16, WiN16 = -Wi16 ----------------
__global__ __launch_bounds__(256) void wcvt3_kernel(
    const float* __restrict__ Wr, const float* __restrict__ Wi,
    u16* __restrict__ Wr16, u16* __restrict__ Wi16, u16* __restrict__ WiN16)
{
    const size_t total = NELEMZ / 4;
    for (size_t i = (size_t)blockIdx.x * 256 + threadIdx.x; i < total;
         i += (size_t)gridDim.x * 256) {
        f32x4 c = ((const f32x4*)Wr)[i];
        f32x4 d = ((const f32x4*)Wi)[i];
        u16x4 pc, pd, pn;
#pragma unroll
        for (int j = 0; j < 4; ++j) {
            pc[j] = f2bf(c[j]);
            pd[j] = f2bf(d[j]);
            pn[j] = f2bf(-d[j]);
        }
        ((u16x4*)Wr16)[i] = pc;
        ((u16x4*)Wi16)[i] = pd;
        ((u16x4*)WiN16)[i] = pn;
    }
}

// ---------------- main MoE GEMM: pure-m201 structure, prescaled A ------------
// 512 threads = 8 waves (2M x 4N), per-wave 128x64. Virtual K = 16 seg x 1024.
// A = gate-prescaled bf16 variants (zero in-loop VALU); B in {Wr,Wi,WiN}.
// LDS 160 KB: A 3x32KB (gload for t+2) + B 2x32KB (gload for t+1).
// Per tile 4 phases: {reads -> bar -> lgkm0 -> 16 MFMA -> bar}. B(t+1) issued
// ph0 BEFORE A(t+2) ph1 so FIFO retire at tile-end vmcnt(4) leaves exactly
// A(t+2) in flight (counted wait, never drains the deep prefetch).
__global__ __launch_bounds__(512, 2) void moe_gemm14(
    const u16* __restrict__ zvar,
    const u16* __restrict__ Wr16, const u16* __restrict__ Wi16,
    const u16* __restrict__ WiN16, float* __restrict__ out)
{
    extern __shared__ u16 lds[];  // A slots: 0,16384,32768; B: 49152,65536

    // bm-local XCD remap: hw xcd = linear%8 owns bm in [xcd*4, xcd*4+4).
    const int linear = blockIdx.x + 32 * (blockIdx.y + 4 * blockIdx.z);
    const int xcd = linear & 7;
    const int bm = xcd * 4 + ((linear >> 3) & 3);
    const int grp2 = linear >> 5;   // 0..7
    const int bn = grp2 & 3;
    const int sel = grp2 >> 2;

    const int tid = threadIdx.x;
    const int lane = tid & 63;
    const int wid = tid >> 6;
    const int wr = wid >> 2;   // 0..1
    const int wc = wid & 3;    // 0..3

    // ---- staging addressing (swizzle chunk c ^= row&7, inverse on source) ----
    const int srow = tid >> 3;
    const int schunk = (tid & 7) ^ (srow & 7);
    int arow[4], brow[4];
#pragma unroll
    for (int j = 0; j < 4; ++j) {
        arow[j] = (bm * 256 + srow + j * 64) * DIM + schunk * 8;
        brow[j] = (bn * 256 + srow + j * 64) * DIM + schunk * 8;
    }

    // ---- fragment read addressing (elems) ----
    const int cg = lane >> 4;
    const int l7 = lane & 7;
    const int ach0 = (cg ^ l7) * 8;
    const int ach1 = ((4 + cg) ^ l7) * 8;
    const int arbase = (wr * 128 + (lane & 15)) * BK;
    const int brbase = (wc * 64 + (lane & 15)) * BK;

    f32x4 acc[8][4];
#pragma unroll
    for (int m = 0; m < 8; ++m)
#pragma unroll
        for (int n = 0; n < 4; ++n) acc[m][n] = (f32x4){0.f, 0.f, 0.f, 0.f};

    // ---- segment state: A tracks t+2, B tracks t+1 ----
    // A variant index: (half^sel)==0 -> zrg[e] (=e), else zig[e] (=8+e).
    const u16* Avar = zvar + (size_t)(sel ? 8 : 0) * NELEMZ;  // seg0: e=0
    const u16* Bh0 = Wr16;
    const u16* Bh1 = sel ? Wi16 : WiN16;
    const u16* Bseg = Bh0;                                     // seg0

    // ---- prologue: gload A(0)->aslot0, A(1)->aslot1, B(0)->bslot0 ----
    {
#pragma unroll
        for (int j = 0; j < 4; ++j) GLOAD16(Avar + arow[j], &lds[(j * 512 + tid) * 8]);
#pragma unroll
        for (int j = 0; j < 4; ++j) GLOAD16(Avar + arow[j] + BK, &lds[16384 + (j * 512 + tid) * 8]);
#pragma unroll
        for (int j = 0; j < 4; ++j) GLOAD16(Bseg + brow[j], &lds[49152 + (j * 512 + tid) * 8]);
        asm volatile("s_waitcnt vmcnt(0)" ::: "memory");
        __builtin_amdgcn_s_barrier();
    }

    int ars = 0;  // A read slot = t%3
#pragma unroll 1
    for (int t = 0; t < NT; ++t) {
        const int t1 = t + 1, t2 = t + 2;
        if ((t1 & 15) == 0) {  // B state for tile t+1
            const int seg = t1 >> 4;            // 1..16 (16 dead-wraps)
            const int e = (seg >> 1) & 7;
            Bseg = ((seg & 1) ? Bh1 : Bh0) + (size_t)e * DIM * DIM;
        }
        if ((t2 & 15) == 0) {  // A state for tile t+2
            const int seg = t2 >> 4;
            const int e = (seg >> 1) & 7;
            const int half = seg & 1;
            Avar = zvar + (size_t)(((half ^ sel) ? 8 : 0) + e) * NELEMZ;
        }
        const int kb1 = (t1 & 15) << 6;              // B staging k base
        const int ka2 = (t2 & 15) << 6;              // A staging k base
        const int aw = (ars == 0) ? 2 : ars - 1;     // (t+2)%3  [r11 formula]
        const int brs = t & 1;
        const int ab = ars * 16384 + arbase;             // A read base
        const int bb = 49152 + brs * 16384 + brbase;     // B read base
        const int sa = aw * 16384;                       // A staging dest
        const int sb = 49152 + (brs ^ 1) * 16384;        // B staging dest

        // ==== ph0: issue B(t+1) gloads; dsr b0+a0; bar; MFMA m0-3 x b0 ====
        GLOAD16(Bseg + brow[0] + kb1, &lds[sb + (0 * 512 + tid) * 8]);
        GLOAD16(Bseg + brow[1] + kb1, &lds[sb + (1 * 512 + tid) * 8]);
        GLOAD16(Bseg + brow[2] + kb1, &lds[sb + (2 * 512 + tid) * 8]);
        GLOAD16(Bseg + brow[3] + kb1, &lds[sb + (3 * 512 + tid) * 8]);
        s16x8 b0[4], a0[4];
#pragma unroll
        for (int n = 0; n < 4; ++n) b0[n] = *(const s16x8*)&lds[bb + n * 1024 + ach0];
#pragma unroll
        for (int m = 0; m < 4; ++m) a0[m] = *(const s16x8*)&lds[ab + m * 1024 + ach0];
        SGB();
        __builtin_amdgcn_s_barrier();
        asm volatile("s_waitcnt lgkmcnt(0)" ::: "memory");
        SGB();
        __builtin_amdgcn_s_setprio(1);
#pragma unroll
        for (int m = 0; m < 4; ++m)
#pragma unroll
            for (int n = 0; n < 4; ++n) acc[m][n] = MFMA16(a0[m], b0[n], acc[m][n]);
        __builtin_amdgcn_s_setprio(0);
        SGB();
        __builtin_amdgcn_s_barrier();

        // ==== ph1: issue A(t+2) gloads; dsr a1; bar; MFMA m4-7 x b0 ====
        GLOAD16(Avar + arow[0] + ka2, &lds[sa + (0 * 512 + tid) * 8]);
        GLOAD16(Avar + arow[1] + ka2, &lds[sa + (1 * 512 + tid) * 8]);
        GLOAD16(Avar + arow[2] + ka2, &lds[sa + (2 * 512 + tid) * 8]);
        GLOAD16(Avar + arow[3] + ka2, &lds[sa + (3 * 512 + tid) * 8]);
        s16x8 a1[4];
#pragma unroll
        for (int m = 0; m < 4; ++m) a1[m] = *(const s16x8*)&lds[ab + (m + 4) * 1024 + ach0];
        SGB();
        __builtin_amdgcn_s_barrier();
        asm volatile("s_waitcnt lgkmcnt(0)" ::: "memory");
        SGB();
        __builtin_amdgcn_s_setprio(1);
#pragma unroll
        for (int m = 0; m < 4; ++m)
#pragma unroll
            for (int n = 0; n < 4; ++n) acc[m + 4][n] = MFMA16(a1[m], b0[n], acc[m + 4][n]);
        __builtin_amdgcn_s_setprio(0);
        SGB();
        __builtin_amdgcn_s_barrier();

        // ==== ph2: dsr b1+a2; bar; MFMA m0-3 x b1 ====
        s16x8 b1[4], a2[4];
#pragma unroll
        for (int n = 0; n < 4; ++n) b1[n] = *(const s16x8*)&lds[bb + n * 1024 + ach1];
#pragma unroll
        for (int m = 0; m < 4; ++m) a2[m] = *(const s16x8*)&lds[ab + m * 1024 + ach1];
        SGB();
        __builtin_amdgcn_s_barrier();
        asm volatile("s_waitcnt lgkmcnt(0)" ::: "memory");
        SGB();
        __builtin_amdgcn_s_setprio(1);
#pragma unroll
        for (int m = 0; m < 4; ++m)
#pragma unroll
            for (int n = 0; n < 4; ++n) acc[m][n] = MFMA16(a2[m], b1[n], acc[m][n]);
        __builtin_amdgcn_s_setprio(0);
        SGB();
        __builtin_amdgcn_s_barrier();

        // ==== ph3: dsr a3; bar; MFMA m4-7 x b1; counted vmcnt(4); bar ====
        s16x8 a3[4];
#pragma unroll
        for (int m = 0; m < 4; ++m) a3[m] = *(const s16x8*)&lds[ab + (m + 4) * 1024 + ach1];
        SGB();
        __builtin_amdgcn_s_barrier();
        asm volatile("s_waitcnt lgkmcnt(0)" ::: "memory");
        SGB();
        __builtin_amdgcn_s_setprio(1);
#pragma unroll
        for (int m = 0; m < 4; ++m)
#pragma unroll
            for (int n = 0; n < 4; ++n) acc[m + 4][n] = MFMA16(a3[m], b1[n], acc[m + 4][n]);
        __builtin_amdgcn_s_setprio(0);
        // retire B(t+1) (and older); keep A(t+2)'s 4 gloads in flight.
        asm volatile("s_waitcnt vmcnt(4)" ::: "memory");
        SGB();
        __builtin_amdgcn_s_barrier();

        ars = (ars == 2) ? 0 : ars + 1;
    }
    asm volatile("s_waitcnt vmcnt(0)" ::: "memory");  // retire dead prefetches

    // ---- epilogue: C[row][col], col=lane&15, row=(lane>>4)*4+j (m89 layout) ----
    float* op = out + (size_t)sel * NTOK * DIM;
    const int col0 = bn * 256 + wc * 64 + (lane & 15);
    const int row0 = bm * 256 + wr * 128 + ((lane >> 4) << 2);
#pragma unroll
    for (int m = 0; m < 8; ++m)
#pragma unroll
        for (int n = 0; n < 4; ++n)
#pragma unroll
            for (int j = 0; j < 4; ++j)
                op[(size_t)(row0 + m * 16 + j) * DIM + col0 + n * 16] = acc[m][n][j];
}

// ================= fallback path: r8 (proven 522 us GEMM) =================
__global__ __launch_bounds__(256) void cvt4_kernel(
    const float* __restrict__ zr, const float* __restrict__ zi,
    const float* __restrict__ Wr, const float* __restrict__ Wi,
    u16* __restrict__ zr16, u16* __restrict__ zi16,
    u16* __restrict__ Wr16, u16* __restrict__ Wi16)
{
    const size_t total = NELEMZ / 4;
    for (size_t i = (size_t)blockIdx.x * 256 + threadIdx.x; i < total;
         i += (size_t)gridDim.x * 256) {
        f32x4 a = ((const f32x4*)zr)[i];
        f32x4 b = ((const f32x4*)zi)[i];
        f32x4 c = ((const f32x4*)Wr)[i];
        f32x4 d = ((const f32x4*)Wi)[i];
        u16x4 pa, pb, pc, pd;
#pragma unroll
        for (int j = 0; j < 4; ++j) {
            pa[j] = f2bf(a[j]); pb[j] = f2bf(b[j]);
            pc[j] = f2bf(c[j]); pd[j] = f2bf(d[j]);
        }
        ((u16x4*)zr16)[i] = pa;
        ((u16x4*)zi16)[i] = pb;
        ((u16x4*)Wr16)[i] = pc;
        ((u16x4*)Wi16)[i] = pd;
    }
}

__global__ __launch_bounds__(512, 2) void moe_gemm8(
    const u16* __restrict__ zr16, const u16* __restrict__ zi16,
    const u16* __restrict__ Wr16, const u16* __restrict__ Wi16,
    const float* __restrict__ gates, float* __restrict__ out)
{
    extern __shared__ u16 lds[];
    const int linear = blockIdx.x + 32 * (blockIdx.y + 4 * blockIdx.z);
    const int xcd = linear & 7;
    const int bm = xcd * 4 + ((linear >> 3) & 3);
    const int grp2 = linear >> 5;
    const int bn = grp2 & 3;
    const int sel = grp2 >> 2;
    const int tid = threadIdx.x;
    const int lane = tid & 63;
    const int wid = tid >> 6;
    const int wr = wid >> 2, wc = wid & 3;
    const int srow = tid >> 3;
    const int schunk = (tid & 7) ^ (srow & 7);
    int arow[4], gidx[4], brow[4];
#pragma unroll
    for (int j = 0; j < 4; ++j) {
        const int gr = bm * 256 + srow + j * 64;
        arow[j] = gr * DIM + schunk * 8;
        gidx[j] = gr * NEXP;
        brow[j] = (bn * 256 + srow + j * 64) * DIM + schunk * 8;
    }
    const int cg = lane >> 4, l7 = lane & 7;
    const int ach0 = (cg ^ l7) * 8;
    const int ach1 = ((4 + cg) ^ l7) * 8;
    const int arbase = (wr * 128 + (lane & 15)) * BK;
    const int brbase = (wc * 64 + (lane & 15)) * BK;
    f32x4 acc[8][4];
#pragma unroll
    for (int m = 0; m < 8; ++m)
#pragma unroll
        for (int n = 0; n < 4; ++n) acc[m][n] = (f32x4){0.f, 0.f, 0.f, 0.f};
    const u16* Asrc = sel ? zi16 : zr16;
    const u16* Bseg = Wr16;
    float sg[4];
#pragma unroll
    for (int j = 0; j < 4; ++j) sg[j] = gates[gidx[j]];
    {
        s16x8 ga[4];
#pragma unroll
        for (int j = 0; j < 4; ++j) ga[j] = *(const s16x8*)(Asrc + arow[j]);
#pragma unroll
        for (int i = 0; i < 4; ++i) GLOAD16(Bseg + brow[i], &lds[32768 + (i * 512 + tid) * 8]);
#pragma unroll
        for (int i = 0; i < 4; ++i) GLOAD16(Bseg + brow[i] + 64, &lds[32768 + 16384 + (i * 512 + tid) * 8]);
#pragma unroll
        for (int j = 0; j < 4; ++j) {
            s16x8 w;
#pragma unroll
            for (int q = 0; q < 8; ++q) w[q] = (short)f2bf(bf2f((u16)ga[j][q]) * sg[j]);
            *(s16x8*)&lds[(tid + j * 512) * 8] = w;
        }
        asm volatile("s_waitcnt vmcnt(4) lgkmcnt(0)" ::: "memory");
        __builtin_amdgcn_s_barrier();
    }
    int br = 0;
#pragma unroll 1
    for (int t = 0; t < NT; ++t) {
        const int tn1 = t + 1, tn2 = t + 2;
        if ((tn1 & 15) == 0) {
            const int seg = tn1 >> 4;
            const int e = (seg >> 1) & 7;
            const int half = seg & 1;
            Asrc = (half ^ sel) ? zi16 : zr16;
            const float sgn = (sel == 0 && half == 1) ? -1.f : 1.f;
#pragma unroll
            for (int j = 0; j < 4; ++j) sg[j] = sgn * gates[gidx[j] + e];
        }
        if ((tn2 & 15) == 0) {
            const int seg = tn2 >> 4;
            const int e = (seg >> 1) & 7;
            Bseg = ((seg & 1) ? Wi16 : Wr16) + (size_t)e * DIM * DIM;
        }
        const int ka = (tn1 & 15) << 6;
        const int kb = (tn2 & 15) << 6;
        const int bs = (br == 0) ? 2 : br - 1;
        const int ab = ((t & 1) << 14) + arbase;
        const int bb = 32768 + br * 16384 + brbase;
        const int sa = ((tn1 & 1) << 14);
        const int sbB = 32768 + bs * 16384;
        s16x8 ga[4];
#pragma unroll
        for (int j = 0; j < 4; ++j) ga[j] = *(const s16x8*)(Asrc + arow[j] + ka);
        GLOAD16(Bseg + brow[0] + kb, &lds[sbB + (0 * 512 + tid) * 8]);
        GLOAD16(Bseg + brow[1] + kb, &lds[sbB + (1 * 512 + tid) * 8]);
        GLOAD16(Bseg + brow[2] + kb, &lds[sbB + (2 * 512 + tid) * 8]);
        GLOAD16(Bseg + brow[3] + kb, &lds[sbB + (3 * 512 + tid) * 8]);
        s16x8 b0[4], a0[4], a1[4], b1[4], a2[4], a3[4];
#pragma unroll
        for (int n = 0; n < 4; ++n) b0[n] = *(const s16x8*)&lds[bb + n * 1024 + ach0];
#pragma unroll
        for (int m = 0; m < 4; ++m) a0[m] = *(const s16x8*)&lds[ab + m * 1024 + ach0];
#pragma unroll
        for (int m = 0; m < 4; ++m) a1[m] = *(const s16x8*)&lds[ab + (m + 4) * 1024 + ach0];
        SGB();
        __builtin_amdgcn_s_setprio(1);
#pragma unroll
        for (int m = 0; m < 4; ++m)
#pragma unroll
            for (int n = 0; n < 4; ++n) acc[m][n] = MFMA16(a0[m], b0[n], acc[m][n]);
        __builtin_amdgcn_s_setprio(0);
#pragma unroll
        for (int n = 0; n < 4; ++n) b1[n] = *(const s16x8*)&lds[bb + n * 1024 + ach1];
#pragma unroll
        for (int m = 0; m < 4; ++m) a2[m] = *(const s16x8*)&lds[ab + m * 1024 + ach1];
        SGB();
        __builtin_amdgcn_s_setprio(1);
#pragma unroll
        for (int m = 0; m < 4; ++m)
#pragma unroll
            for (int n = 0; n < 4; ++n) acc[m + 4][n] = MFMA16(a1[m], b0[n], acc[m + 4][n]);
        __builtin_amdgcn_s_setprio(0);
#pragma unroll
        for (int j = 0; j < 2; ++j) {
            s16x8 w;
#pragma unroll
            for (int q = 0; q < 8; ++q) w[q] = (short)f2bf(bf2f((u16)ga[j][q]) * sg[j]);
            *(s16x8*)&lds[sa + (tid + j * 512) * 8] = w;
        }
#pragma unroll
        for (int m = 0; m < 4; ++m) a3[m] = *(const s16x8*)&lds[ab + (m + 4) * 1024 + ach1];
        SGB();
        __builtin_amdgcn_s_setprio(1);
#pragma unroll
        for (int m = 0; m < 4; ++m)
#pragma unroll
            for (int n = 0; n < 4; ++n) acc[m][n] = MFMA16(a2[m], b1[n], acc[m][n]);
        __builtin_amdgcn_s_setprio(0);
#pragma unroll
        for (int j = 2; j < 4; ++j) {
            s16x8 w;
#pragma unroll
            for (int q = 0; q < 8; ++q) w[q] = (short)f2bf(bf2f((u16)ga[j][q]) * sg[j]);
            *(s16x8*)&lds[sa + (tid + j * 512) * 8] = w;
        }
        __builtin_amdgcn_s_setprio(1);
#pragma unroll
        for (int m = 0; m < 4; ++m)
#pragma unroll
            for (int n = 0; n < 4; ++n) acc[m + 4][n] = MFMA16(a3[m], b1[n], acc[m + 4][n]);
        __builtin_amdgcn_s_setprio(0);
        asm volatile("s_waitcnt vmcnt(4) lgkmcnt(0)" ::: "memory");
        __builtin_amdgcn_s_barrier();
        br = (br == 2) ? 0 : br + 1;
    }
    asm volatile("s_waitcnt vmcnt(0)" ::: "memory");
    float* op = out + (size_t)sel * NTOK * DIM;
    const int col0 = bn * 256 + wc * 64 + (lane & 15);
    const int row0 = bm * 256 + wr * 128 + ((lane >> 4) << 2);
#pragma unroll
    for (int m = 0; m < 8; ++m)
#pragma unroll
        for (int n = 0; n < 4; ++n)
#pragma unroll
            for (int j = 0; j < 4; ++j)
                op[(size_t)(row0 + m * 16 + j) * DIM + col0 + n * 16] = acc[m][n][j];
}

extern "C" void kernel_launch(void* const* d_in, const int* in_sizes, int n_in,
                              void* d_out, int out_size, void* d_ws, size_t ws_size,
                              hipStream_t stream) {
    const float* zr = (const float*)d_in[0];
    const float* zi = (const float*)d_in[1];
    const float* Wg = (const float*)d_in[2];
    const float* bg = (const float*)d_in[3];
    const float* Wr = (const float*)d_in[4];
    const float* Wi = (const float*)d_in[5];
    float* out = (float*)d_out;

    const size_t need_new = (16 + 3) * NELEMZ * sizeof(u16)
                          + (size_t)NTOK * NEXP * sizeof(float) + 1024;

    if (ws_size >= need_new) {
        u16* zvar = (u16*)d_ws;                 // 16 x NELEMZ
        u16* Wr16 = zvar + 16 * NELEMZ;
        u16* Wi16 = Wr16 + NELEMZ;
        u16* WiN16 = Wi16 + NELEMZ;
        float* gates = (float*)(WiN16 + NELEMZ);

        gates_kernel<<<NTOK / 4, 256, 0, stream>>>(zr, zi, Wg, bg, gates);
        prez_kernel<<<2048, 256, 0, stream>>>(zr, zi, gates, zvar);
        wcvt3_kernel<<<2048, 256, 0, stream>>>(Wr, Wi, Wr16, Wi16, WiN16);

        hipFuncSetAttribute((const void*)moe_gemm14,
                            hipFuncAttributeMaxDynamicSharedMemorySize, 163840);
        dim3 grid(NTOK / 256, DIM / 256, 2);
        moe_gemm14<<<grid, 512, 163840, stream>>>(zvar, Wr16, Wi16, WiN16, out);
    } else {
        u16* zr16 = (u16*)d_ws;
        u16* zi16 = zr16 + NELEMZ;
        u16* Wr16 = zi16 + NELEMZ;
        u16* Wi16 = Wr16 + NELEMZ;
        float* gates = (float*)(Wi16 + NELEMZ);

        cvt4_kernel<<<2048, 256, 0, stream>>>(zr, zi, Wr, Wi, zr16, zi16, Wr16, Wi16);
        gates_kernel<<<NTOK / 4, 256, 0, stream>>>(zr, zi, Wg, bg, gates);

        hipFuncSetAttribute((const void*)moe_gemm8,
                            hipFuncAttributeMaxDynamicSharedMemorySize, 163840);
        dim3 grid(NTOK / 256, DIM / 256, 2);
        moe_gemm8<<<grid, 512, 163840, stream>>>(zr16, zi16, Wr16, Wi16, gates, out);
    }
}